// Round 19
// baseline (307.015 us; speedup 1.0000x reference)
//
#include <hip/hip_runtime.h>
#include <hip/hip_bf16.h>
#include <math.h>

// ---------------- constants ----------------
#define BATCH   16
#define TFRM    4096          // frames per batch (= L)
#define DIM     512
#define NFFT    1024
#define HOP     256
#define PADC    384           // (WIN-HOP)/2
#define MROWS   (BATCH*TFRM)  // 65536
#define OUTLEN  1048576       // per-batch output samples
#define TWO_PI_OVER_N 0.006135923151542565f  // 2*pi/1024
#define INV_TWO_PI    0.15915494309189535f   // 1/(2*pi)

typedef __bf16 bf16x8 __attribute__((ext_vector_type(8)));
typedef float  f32x16 __attribute__((ext_vector_type(16)));

__device__ __forceinline__ ushort f2bf(float f) {
  union { float f; unsigned u; } v; v.f = f;
  unsigned u = v.u;
  unsigned r = (u + 0x7FFFu + ((u >> 16) & 1u)) >> 16;
  return (ushort)r;
}
__device__ __forceinline__ float bf2f(ushort h) {
  union { unsigned u; float f; } v; v.u = ((unsigned)h) << 16;
  return v.f;
}
// HW transcendentals (single VALU op each; v_sin/v_cos take revolutions).
__device__ __forceinline__ float fast_sin(float x) { return __builtin_amdgcn_sinf(x * INV_TWO_PI); }
__device__ __forceinline__ float fast_cos(float x) { return __builtin_amdgcn_cosf(x * INV_TWO_PI); }
__device__ __forceinline__ float fast_exp(float x) { return __builtin_amdgcn_exp2f(x * 1.4426950408889634f); }
// lane-xor-1 exchange as a single VALU DPP op (quad_perm [1,0,3,2] = 0xB1).
__device__ __forceinline__ float dpp_xor1(float v) {
  return __int_as_float(__builtin_amdgcn_update_dpp(
      __float_as_int(v), __float_as_int(v), 0xB1, 0xF, 0xF, false));
}
__device__ __forceinline__ f32x16 MF(bf16x8 a, bf16x8 b, f32x16 c) {
  return __builtin_amdgcn_mfma_f32_32x32x16_bf16(a, b, c, 0, 0, 0);
}

// ---------------- prep: x fp32 -> bf16 FRAGMENT-MAJOR, fused Nyquist GEMV ----------------
// frag(rg,t): idx = ((rg*32+t)*64 + l)*8 + j holds x[rg*32+(l&31)][t*16+(l>>5)*8+j].
// One wave per row: lane covers cols lane*8..+8 -> t = lane>>1, kh = lane&1, one 16B chunk.
__global__ void k_prep_x(const float* __restrict__ x, const float* __restrict__ W,
                         const float* __restrict__ bias,
                         ushort* __restrict__ xbf, float* __restrict__ s512) {
  const int row  = blockIdx.x * 4 + (threadIdx.x >> 6);
  const int lane = threadIdx.x & 63;
  const float* xr = x + (size_t)row * DIM + lane * 8;
  float4 v0 = *(const float4*)xr;
  float4 v1 = *(const float4*)(xr + 4);
  ushort4 u0, u1;
  u0.x = f2bf(v0.x); u0.y = f2bf(v0.y); u0.z = f2bf(v0.z); u0.w = f2bf(v0.w);
  u1.x = f2bf(v1.x); u1.y = f2bf(v1.y); u1.z = f2bf(v1.z); u1.w = f2bf(v1.w);
  size_t off = ((((size_t)(row >> 5) * 32 + (lane >> 1)) * 64) +
                ((lane & 1) << 5) + (row & 31)) * 8;
  *(ushort4*)(xbf + off)     = u0;
  *(ushort4*)(xbf + off + 4) = u1;
  const float* w0 = W + 512 * DIM + lane * 8;    // mag row k=512
  const float* w1 = W + 1025 * DIM + lane * 8;   // phase row k=512
  float4 a0 = *(const float4*)w0, a1 = *(const float4*)(w0 + 4);
  float4 b0 = *(const float4*)w1, b1 = *(const float4*)(w1 + 4);
  float sm = v0.x*a0.x + v0.y*a0.y + v0.z*a0.z + v0.w*a0.w
           + v1.x*a1.x + v1.y*a1.y + v1.z*a1.z + v1.w*a1.w;
  float sp = v0.x*b0.x + v0.y*b0.y + v0.z*b0.z + v0.w*b0.w
           + v1.x*b1.x + v1.y*b1.y + v1.z*b1.z + v1.w*b1.w;
#pragma unroll
  for (int off2 = 32; off2; off2 >>= 1) {
    sm += __shfl_down(sm, off2);
    sp += __shfl_down(sp, off2);
  }
  if (lane == 0) {
    float mag = fminf(fast_exp(sm + bias[512]), 100.0f);
    s512[row] = mag * fast_cos(sp + bias[1025]) * (1.0f / 1024.0f);
  }
}

// ---------------- prep: W -> bf16 FRAGMENT-MAJOR [32 rg][32 t][64][8]
// Logical interleaved row r (0..1023): r=2k -> orig mag row k; r=2k+1 -> orig phase 513+k.
__global__ void k_prep_w(const float* __restrict__ W, ushort* __restrict__ o) {
  int i = blockIdx.x * 256 + threadIdx.x;          // over 1024*512
  int j    = i & 7;
  int lane = (i >> 3) & 63;
  int ft   = i >> 9;                               // rg*32 + t
  int t    = ft & 31;
  int rg   = ft >> 5;
  int r    = rg * 32 + (lane & 31);
  int col  = t * 16 + ((lane >> 5) << 3) + j;
  int orig = (r >> 1) + (r & 1) * 513;
  o[i] = f2bf(W[orig * DIM + col]);
}

// ---------------- basis: BasE/BasO FRAGMENT-MAJOR [16 rg][32 t][64][8]
// Logical row r -> output sample n = r+1.
__global__ void k_basis(ushort* __restrict__ basE, ushort* __restrict__ basO) {
  int i = blockIdx.x * 256 + threadIdx.x;          // over 512*512
  int j    = i & 7;
  int lane = (i >> 3) & 63;
  int ft   = i >> 9;
  int t    = ft & 31;
  int rg   = ft >> 5;
  int r    = rg * 32 + (lane & 31);
  int k    = t * 16 + ((lane >> 5) << 3) + j;
  int n    = r + 1;
  float e, o;
  if (k == 0) { e = 1.0f / 1024.0f; o = 0.0f; }
  else {
    int ph = (k * n) & 1023;                       // exact integer phase reduction
    float ang = (float)ph * TWO_PI_OVER_N;
    e = 2.0f * cosf(ang) * (1.0f / 1024.0f);
    o = 2.0f * sinf(ang) * (1.0f / 1024.0f);
  }
  basE[i] = f2bf(e);
  basO[i] = f2bf(o);
}

#define LDG2(dst, ptr) asm volatile("global_load_dwordx4 %0, %1, off" : "=v"(dst) : "v"(ptr))

// ---------------- GEMM1 (zero-LDS main loop): h = act(xbf . Wp^T), per-wave 64x64 tiles
// M=65536, Nlogical=1024 (interleaved), K=512. 16384 independent waves; A (xbf) and
// B (Wp) both FRAGMENT-MAJOR -> every operand load is 64 lanes x 16B contiguous.
// Untracked inline-asm loads + manual vmcnt(4) ladder + sched_barrier(0) (rule #18);
// FIFO identical to k_gemm2 (proven r18). No __syncthreads anywhere; epilogue
// transposes through per-wave-private LDS [64][72] (144B row stride: 16B-aligned
// b128 readback) and stores h_a/h_b fragment-major for GEMM2.
__global__ __launch_bounds__(256) void k_gemm1z(const ushort* __restrict__ A,
                                                const ushort* __restrict__ B,
                                                ushort* __restrict__ Ca, ushort* __restrict__ Cb,
                                                const float* __restrict__ bias) {
  __shared__ __align__(16) ushort lds[4][64 * 72];   // per-wave private 9.2KB regions
  const int tid  = threadIdx.x;
  const int cpx  = gridDim.x >> 3;
  const int bid  = ((int)blockIdx.x & 7) * cpx + ((int)blockIdx.x >> 3);   // XCD-chunked
  const int wv   = tid >> 6;
  const int lane = tid & 63;
  const int wid  = bid * 4 + wv;                 // 0..16383
  const int mt   = wid >> 4;                     // M-tile 0..1023 (64 rows)
  const int nt   = wid & 15;                     // N-tile 0..15 (64 interleaved cols)

  const ushort* pa0 = A + (((size_t)(mt * 2) * 32) * 64 + lane) * 8;
  const ushort* pa1 = pa0 + (size_t)32 * 64 * 8;
  const ushort* pb0 = B + (((size_t)(nt * 2) * 32) * 64 + lane) * 8;
  const ushort* pb1 = pb0 + (size_t)32 * 64 * 8;

  f32x16 acc[2][2] = {};
  bf16x8 aE0, aE1, bE0, bE1, aO0, aO1, bO0, bO1;   // named dbuf sets (rule #20)

#define LOADSET_E1(toff) { LDG2(aE0, pa0 + (toff) * 512); LDG2(aE1, pa1 + (toff) * 512); \
                           LDG2(bE0, pb0 + (toff) * 512); LDG2(bE1, pb1 + (toff) * 512); }
#define LOADSET_O1(toff) { LDG2(aO0, pa0 + (toff) * 512); LDG2(aO1, pa1 + (toff) * 512); \
                           LDG2(bO0, pb0 + (toff) * 512); LDG2(bO1, pb1 + (toff) * 512); }

  LOADSET_E1(0);
  LOADSET_O1(1);
  asm volatile("s_waitcnt vmcnt(4)" ::: "memory");
  __builtin_amdgcn_sched_barrier(0);

#pragma unroll
  for (int t = 0; t < 32; t += 2) {
    acc[0][0] = MF(aE0, bE0, acc[0][0]); acc[0][1] = MF(aE0, bE1, acc[0][1]);
    acc[1][0] = MF(aE1, bE0, acc[1][0]); acc[1][1] = MF(aE1, bE1, acc[1][1]);
    if (t + 2 < 32) { LOADSET_E1(t + 2); asm volatile("s_waitcnt vmcnt(4)" ::: "memory"); }
    else            { asm volatile("s_waitcnt vmcnt(0)" ::: "memory"); }
    __builtin_amdgcn_sched_barrier(0);
    acc[0][0] = MF(aO0, bO0, acc[0][0]); acc[0][1] = MF(aO0, bO1, acc[0][1]);
    acc[1][0] = MF(aO1, bO0, acc[1][0]); acc[1][1] = MF(aO1, bO1, acc[1][1]);
    if (t + 2 < 32) {
      LOADSET_O1(t + 3);
      asm volatile("s_waitcnt vmcnt(4)" ::: "memory");
      __builtin_amdgcn_sched_barrier(0);
    }
  }

  // ---- epilogue: activation (DPP pairing), de-interleave, frag-major h store ----
  ushort* wl = &lds[wv][0];
  const int kh  = lane >> 5;
  const int l31 = lane & 31;
  const bool odd = lane & 1;                    // col parity == l31&1
#pragma unroll
  for (int n = 0; n < 2; ++n) {
    const int kcol = n * 16 + (l31 >> 1);       // 0..31 within wave k-window
    const int kk   = nt * 32 + kcol;            // global k
    const float bs = bias[odd ? 513 + kk : kk];
    const int dcol = (odd ? 32 : 0) + kcol;     // LDS: h_a cols 0-31, h_b cols 32-63
#pragma unroll
    for (int m = 0; m < 2; ++m)
#pragma unroll
      for (int q = 0; q < 4; ++q)
#pragma unroll
        for (int rr = 0; rr < 4; ++rr) {
          const int lrow = m * 32 + q * 8 + (kh << 2) + rr;
          float v = acc[m][n][q * 4 + rr] + bs;
          float pv = dpp_xor1(v);
          float hm = odd ? pv : v;
          float hp = odd ? v : pv;
          float mag = fminf(fast_exp(hm), 100.0f);
          float outv = odd ? mag * fast_sin(hp) : mag * fast_cos(hp);
          wl[lrow * 72 + dcol] = f2bf(outv);
        }
  }
  // same-wave LDS write->read ordering via compiler lgkmcnt; frag-major readback+store
#pragma unroll
  for (int half = 0; half < 2; ++half) {
    ushort* Cx = half ? Cb : Ca;
#pragma unroll
    for (int rgl = 0; rgl < 2; ++rgl)
#pragma unroll
      for (int tl = 0; tl < 2; ++tl) {
        const int rrow = rgl * 32 + l31;
        const int ccol = half * 32 + tl * 16 + (kh << 3);
        bf16x8 v = *(const bf16x8*)(wl + rrow * 72 + ccol);
        size_t go = (((size_t)(mt * 2 + rgl) * 32 + (nt * 2 + tl)) * 64 + lane) * 8;
        *(bf16x8*)(Cx + go) = v;
      }
  }
#undef LOADSET_E1
#undef LOADSET_O1
}

// ---------------- GEMM2: zero-LDS, zero-barrier, per-wave 64x64 tiles (r18, proven) ----
// E = h_a . BasE^T (+ Nyquist fold), O = h_b . BasO^T, both M=65536 N=512 K=512.
__global__ __launch_bounds__(256) void k_gemm2(const ushort* __restrict__ hA,
                                               const ushort* __restrict__ hB,
                                               const ushort* __restrict__ basE,
                                               const ushort* __restrict__ basO,
                                               ushort* __restrict__ E, ushort* __restrict__ O,
                                               const float* __restrict__ s512) {
  __shared__ __align__(16) ushort lds[4][64 * 72];   // per-wave private regions
  const int tid  = threadIdx.x;
  const int cpx  = gridDim.x >> 3;
  const int bid  = ((int)blockIdx.x & 7) * cpx + ((int)blockIdx.x >> 3);   // XCD-chunked
  const int wv   = tid >> 6;
  const int lane = tid & 63;
  const int wid  = bid * 4 + wv;                 // 0..16383
  const bool isO = wid >= 8192;
  const int w    = wid & 8191;
  const int mt   = w >> 3;                       // M-tile 0..1023 (64 rows)
  const int nt   = w & 7;                        // N-tile 0..7 (64 cols)
  const ushort* A  = isO ? hB : hA;
  const ushort* B  = isO ? basO : basE;
  ushort* Cp = isO ? O : E;

  const ushort* pa0 = A + (((size_t)(mt * 2) * 32) * 64 + lane) * 8;
  const ushort* pa1 = pa0 + (size_t)32 * 64 * 8;
  const ushort* pb0 = B + (((size_t)(nt * 2) * 32) * 64 + lane) * 8;
  const ushort* pb1 = pb0 + (size_t)32 * 64 * 8;

  f32x16 acc[2][2] = {};
  bf16x8 aE0, aE1, bE0, bE1, aO0, aO1, bO0, bO1;

#define LOADSET_E(toff) { LDG2(aE0, pa0 + (toff) * 512); LDG2(aE1, pa1 + (toff) * 512); \
                          LDG2(bE0, pb0 + (toff) * 512); LDG2(bE1, pb1 + (toff) * 512); }
#define LOADSET_O(toff) { LDG2(aO0, pa0 + (toff) * 512); LDG2(aO1, pa1 + (toff) * 512); \
                          LDG2(bO0, pb0 + (toff) * 512); LDG2(bO1, pb1 + (toff) * 512); }

  LOADSET_E(0);
  LOADSET_O(1);
  asm volatile("s_waitcnt vmcnt(4)" ::: "memory");
  __builtin_amdgcn_sched_barrier(0);

#pragma unroll
  for (int t = 0; t < 32; t += 2) {
    acc[0][0] = MF(aE0, bE0, acc[0][0]); acc[0][1] = MF(aE0, bE1, acc[0][1]);
    acc[1][0] = MF(aE1, bE0, acc[1][0]); acc[1][1] = MF(aE1, bE1, acc[1][1]);
    if (t + 2 < 32) { LOADSET_E(t + 2); asm volatile("s_waitcnt vmcnt(4)" ::: "memory"); }
    else            { asm volatile("s_waitcnt vmcnt(0)" ::: "memory"); }
    __builtin_amdgcn_sched_barrier(0);
    acc[0][0] = MF(aO0, bO0, acc[0][0]); acc[0][1] = MF(aO0, bO1, acc[0][1]);
    acc[1][0] = MF(aO1, bO0, acc[1][0]); acc[1][1] = MF(aO1, bO1, acc[1][1]);
    if (t + 2 < 32) {
      LOADSET_O(t + 3);
      asm volatile("s_waitcnt vmcnt(4)" ::: "memory");
      __builtin_amdgcn_sched_barrier(0);
    }
  }

  // ---- epilogue (per-wave private LDS; no barriers) ----
  ushort* wl = &lds[wv][0];
  const int kh  = lane >> 5;
  const int l31 = lane & 31;
  const bool odd = lane & 1;
#pragma unroll
  for (int m = 0; m < 2; ++m)
#pragma unroll
    for (int q = 0; q < 4; ++q) {
      const int rowb = m * 32 + q * 8 + (kh << 2);
      float4 sv4 = {0.f, 0.f, 0.f, 0.f};
      if (!isO) sv4 = *(const float4*)(s512 + mt * 64 + rowb);
#pragma unroll
      for (int rr = 0; rr < 4; ++rr) {
        const float sv = ((const float*)&sv4)[rr];
        const float par = isO ? 0.0f : (odd ? sv : -sv);
#pragma unroll
        for (int n = 0; n < 2; ++n)
          wl[(rowb + rr) * 72 + n * 32 + l31] = f2bf(acc[m][n][q * 4 + rr] + par);
      }
    }
#pragma unroll
  for (int it = 0; it < 8; ++it) {
    const int lrow = (lane >> 3) + it * 8;
    const int lcol = (lane & 7) << 3;
    bf16x8 v = *(const bf16x8*)(wl + lrow * 72 + lcol);
    *(bf16x8*)(Cp + ((size_t)(mt * 64 + lrow) << 9) + nt * 64 + lcol) = v;
  }
#undef LOADSET_E
#undef LOADSET_O
}

// ---------------- overlap-add (4 samples/thread, aligned vector loads) ----------------
// E/O unshifted: E[i] = E_st[i+1], stride 512. frames[n] = win[n]*(E_st[n] -+ O_st[n]);
// n<=512 direct ('-'), n>512 mirrors to 1024-n ('+'). Nyquist pre-folded into E.
__global__ void k_oa(const ushort* __restrict__ E, const ushort* __restrict__ O,
                     float* __restrict__ out) {
  int u = blockIdx.x * 256 + threadIdx.x;       // 16 * 262144 groups of 4 samples
  int b  = u >> 18;
  int g  = u & 262143;
  int s  = (g << 2) + PADC;
  int t0 = s >> 8;
  int nb = s & 255;                             // multiple of 4
  float acc[4] = {0.f, 0.f, 0.f, 0.f};
  bool interior = (t0 >= 3) && (t0 < TFRM);
  float env[4];
#pragma unroll
  for (int j = 0; j < 4; ++j) env[j] = interior ? 1.5f : 0.0f;
#pragma unroll
  for (int q = 0; q < 4; ++q) {
    int t = t0 - q;
    if (t < 0 || t >= TFRM) continue;
    int n = nb + (q << 8);                      // multiple of 4, in [0, 1020]
    size_t base = ((size_t)(b << 12) + t) << 9; // row * 512
    float w[4];
#pragma unroll
    for (int j = 0; j < 4; ++j) {
      w[j] = 0.5f - 0.5f * __builtin_amdgcn_cosf((float)(n + j) * (1.0f / 1024.0f));
      if (!interior) env[j] += w[j] * w[j];
    }
    float d[4];
    if (n <= 508) {                             // direct: d[j] = E[n+j-1] - O[n+j-1]
      ushort4 e1 = *(const ushort4*)(E + base + n);
      ushort4 o1 = *(const ushort4*)(O + base + n);
      if (n >= 4) {
        ushort4 e0 = *(const ushort4*)(E + base + n - 4);
        ushort4 o0 = *(const ushort4*)(O + base + n - 4);
        d[0] = bf2f(e0.w) - bf2f(o0.w);
      } else d[0] = 0.0f;                       // n==0: w[0]=0 anyway
      d[1] = bf2f(e1.x) - bf2f(o1.x);
      d[2] = bf2f(e1.y) - bf2f(o1.y);
      d[3] = bf2f(e1.z) - bf2f(o1.z);
    } else if (n == 512) {                      // straddle: one aligned load at 508
      ushort4 e = *(const ushort4*)(E + base + 508);
      ushort4 o = *(const ushort4*)(O + base + 508);
      d[0] = bf2f(e.w) - bf2f(o.w);             // O_st[512]=0, sign moot
      d[1] = bf2f(e.z) + bf2f(o.z);
      d[2] = bf2f(e.y) + bf2f(o.y);
      d[3] = bf2f(e.x) + bf2f(o.x);
    } else {                                    // n >= 516 mirror: load at 1020-n
      ushort4 e = *(const ushort4*)(E + base + 1020 - n);
      ushort4 o = *(const ushort4*)(O + base + 1020 - n);
      d[0] = bf2f(e.w) + bf2f(o.w);
      d[1] = bf2f(e.z) + bf2f(o.z);
      d[2] = bf2f(e.y) + bf2f(o.y);
      d[3] = bf2f(e.x) + bf2f(o.x);
    }
#pragma unroll
    for (int j = 0; j < 4; ++j) acc[j] += w[j] * d[j];
  }
  float4 o4;
  o4.x = acc[0] / env[0]; o4.y = acc[1] / env[1];
  o4.z = acc[2] / env[2]; o4.w = acc[3] / env[3];
  *(float4*)(out + (size_t)u * 4) = o4;
}

// ---------------- launch ----------------
extern "C" void kernel_launch(void* const* d_in, const int* in_sizes, int n_in,
                              void* d_out, int out_size, void* d_ws, size_t ws_size,
                              hipStream_t stream) {
  const float* x    = (const float*)d_in[0];
  const float* W    = (const float*)d_in[1];
  const float* bias = (const float*)d_in[2];
  float* out = (float*)d_out;
  char* ws = (char*)d_ws;

  // ws layout (bytes):
  //   [0, 67108864)             xbf bf16 fragment-major (dead after GEMM1)  ALIASED WITH E
  //   [67108864, 134217728)     h_a bf16 fragment-major [2048 rg][32 t][64][8]
  //   [134217728, 201326592)    h_b bf16 fragment-major
  //   [201326592, 268435456)    O  bf16 [65536][512] row-major
  //   [268435456, 269484032)    Wp bf16 fragment-major [32 rg][32 t][64][8]
  //   [269484032, 270008320)    BasE bf16 fragment-major [16 rg][32 t][64][8]
  //   [270008320, 270532608)    BasO bf16 fragment-major
  //   [270532608, 270794752)    s512 fp32 [65536]
  ushort* xbf  = (ushort*)(ws + 0);
  ushort* Epp  = (ushort*)(ws + 0);
  ushort* h_a  = (ushort*)(ws + 67108864);
  ushort* h_b  = (ushort*)(ws + 134217728);
  ushort* Obuf = (ushort*)(ws + 201326592);
  ushort* Wp   = (ushort*)(ws + 268435456);
  ushort* basE = (ushort*)(ws + 269484032);
  ushort* basO = (ushort*)(ws + 270008320);
  float*  s512 = (float*) (ws + 270532608);

  k_prep_x<<<MROWS / 4, 256, 0, stream>>>(x, W, bias, xbf, s512);
  k_prep_w<<<(1024 * 512) / 256, 256, 0, stream>>>(W, Wp);
  k_basis<<<(512 * 512) / 256, 256, 0, stream>>>(basE, basO);

  // GEMM1 (zero-LDS per-wave tiles) + fused activation, fragment-major h output
  k_gemm1z<<<4096, 256, 0, stream>>>(xbf, Wp, h_a, h_b, bias);

  // GEMM2: zero-LDS per-wave tiles; E (+Nyquist fold) and O in one launch
  k_gemm2<<<4096, 256, 0, stream>>>(h_a, h_b, basE, basO, Epp, Obuf, s512);

  // overlap-add, windowing, mirror reconstruction, envelope normalize, crop
  k_oa<<<(BATCH * OUTLEN) / 1024, 256, 0, stream>>>(Epp, Obuf, out);
}